// Round 10
// baseline (612.864 us; speedup 1.0000x reference)
//
#include <hip/hip_runtime.h>
#include <math.h>

#define B_   32
#define L_   2048
#define DSEQ 1024
#define DGLB 1024
#define H_   16
#define DK_  64
#define DV_  64
#define LT   64
#define NT   (L_/LT)      // 32
#define PSTRIDE 66        // m, s, y[64]

// Wc2 layout: [h][ks(32)][j(128)][e(32)] bf16; d = ks*32 + e
#define WC_KSTRIDE 4096            // 128*32 elems per k-step
#define WC_HSTRIDE 131072          // 32*4096 elems per head

#define AS1 __attribute__((address_space(1)))
#define AS3 __attribute__((address_space(3)))

using u16    = unsigned short;
using bf16x8 = __attribute__((ext_vector_type(8))) short;
using f32x4  = __attribute__((ext_vector_type(4))) float;

__device__ __forceinline__ u16 f2bf(float x) {
  union { float f; unsigned int u; } v; v.f = x;
  return (u16)((v.u + 0x7fffu + ((v.u >> 16) & 1u)) >> 16);   // RNE
}

// Wc2[h][d>>5][j][d&31]: j<64 -> Wk[h,:,j], else Wv[h,:,j-64]
__global__ void pack_w_kernel(const float* __restrict__ Wk,
                              const float* __restrict__ Wv,
                              u16* __restrict__ Wc) {
  const int h = blockIdx.x, j = blockIdx.y;
  const float* src = (j < DK_) ? (Wk + (size_t)h*DSEQ*DK_ + j)
                               : (Wv + (size_t)h*DSEQ*DV_ + (j - DK_));
  u16* dst = Wc + (size_t)h*WC_HSTRIDE + (size_t)j*32;
  for (int d = threadIdx.x; d < DSEQ; d += blockDim.x)
    dst[(size_t)(d >> 5)*WC_KSTRIDE + (d & 31)] = f2bf(src[(size_t)d*64]);
}

// S (fp32) -> Sb (bf16), flat; 8-elem granules, coalesced
__global__ void s2bf_kernel(const float* __restrict__ S, u16* __restrict__ Sb) {
  const size_t G = (size_t)B_*L_*DSEQ/8;
  for (size_t i = (size_t)blockIdx.x*256 + threadIdx.x; i < G; i += (size_t)4096*256) {
    const float4* sp = (const float4*)(S + i*8);
    float4 v0 = sp[0], v1 = sp[1];
    bf16x8 wv;
    wv[0]=(short)f2bf(v0.x); wv[1]=(short)f2bf(v0.y);
    wv[2]=(short)f2bf(v0.z); wv[3]=(short)f2bf(v0.w);
    wv[4]=(short)f2bf(v1.x); wv[5]=(short)f2bf(v1.y);
    wv[6]=(short)f2bf(v1.z); wv[7]=(short)f2bf(v1.w);
    *(bf16x8*)(Sb + i*8) = wv;
  }
}

// Q[b][h][k] = tanh(sum_d X[b,d]*Wq[h,d,k]); grid (H, B/4), block 64
__global__ void q_proj_kernel(const float* __restrict__ X,
                              const float* __restrict__ Wq,
                              float* __restrict__ Q) {
  const int h = blockIdx.x, b0 = blockIdx.y*4, k = threadIdx.x;
  const float* w = Wq + (size_t)h*DGLB*DK_ + k;
  float a0=0.f, a1=0.f, a2=0.f, a3=0.f;
  for (int d = 0; d < DGLB; ++d) {
    float wv = w[(size_t)d*DK_];
    a0 += X[(size_t)(b0+0)*DGLB + d]*wv;
    a1 += X[(size_t)(b0+1)*DGLB + d]*wv;
    a2 += X[(size_t)(b0+2)*DGLB + d]*wv;
    a3 += X[(size_t)(b0+3)*DGLB + d]*wv;
  }
  Q[((size_t)(b0+0)*H_+h)*DK_+k] = tanhf(a0);
  Q[((size_t)(b0+1)*H_+h)*DK_+k] = tanhf(a1);
  Q[((size_t)(b0+2)*H_+h)*DK_+k] = tanhf(a2);
  Q[((size_t)(b0+3)*H_+h)*DK_+k] = tanhf(a3);
}

// grid: 8192 linear blocks, 256 threads = 4 waves, 2 blocks/CU.
// OFFSET-DIAGONAL schedule: x = id&7 -> XCD AND head-pair (slot): B slice
// 512 KB stays L2-resident per XCD (r8 property). m = id>>3; tile =
// (m + 128*x) & 1023: the 8 readers of a tile are 128 m-steps apart --
// beyond the ~64-block per-XCD residency window (no concurrent duplicate
// HBM misses, r8 bug) but within the L3 horizon (union working set
// ~128 MB < 256 MB, r9 bug) -> reads 2..8 hit L3.
// Wave w = (head hp=w>>1, K|V=w&1); tile 64 rows x 64 cols, acc[4][4].
// K pipelined in 4 sub-tiles of 256 via 2x32KB LDS dbuf, stage issue-early.
// B prefetch distance 4 (bA..bD static rotation).
// MODE: 0=full, 1=diag-noB (no B refills), 2=diag-noStage (stage s0 only).
template<int BF16SRC, int MODE>
__global__ __launch_bounds__(256, 2) void fused_kernel(
    const float* __restrict__ S, const u16* __restrict__ Sb,
    const u16* __restrict__ Wc, const float* __restrict__ Q,
    float* __restrict__ part) {
  __shared__ u16   Slds[2*64*256];   // 2 x 32 KB, rows 512 B
  __shared__ float lpart[2][64];

  const int id   = blockIdx.x;
  const int slot = id & 7;           // XCD = head-pair
  const int m    = id >> 3;
  const int tile = (m + (slot << 7)) & 1023;
  const int t    = tile & (NT-1), b = tile >> 5;

  const int tid  = threadIdx.x;
  const int wave = tid >> 6, lane = tid & 63;
  const int lhi  = lane >> 4, llo = lane & 15;
  const int isV  = wave & 1,  hp  = wave >> 1;
  const int h    = slot*2 + hp;

  const u16* wb = Wc + (size_t)h*WC_HSTRIDE + (size_t)(isV*64 + llo)*32 + lhi*8;
  const int swz = llo << 4;
  int arow[4];
  #pragma unroll
  for (int rt = 0; rt < 4; ++rt) arow[rt] = (rt*16 + llo)*512;  // bytes

  const u16*   Sv = Sb + ((size_t)b*L_ + (size_t)t*LT)*DSEQ;
  const float* Sf = S  + ((size_t)b*L_ + (size_t)t*LT)*DSEQ;

  // stage sub-tile (64 rows x 256 k) into buf[sub&1] via global_load_lds:
  // chunk j (1 KB LDS) = rows 2j,2j+1; lane l -> row 2j+(l>>5), pos q=l&31,
  // logical granule g = q ^ (row&15) fetched from global (src-side swizzle).
  auto stage_gl = [&](int sub) {
    const int bs = (sub & 1) * 16384;          // u16 offset
    #pragma unroll
    for (int it = 0; it < 8; ++it) {
      const int j   = wave*8 + it;
      const int row = 2*j + (lane >> 5);
      const int g   = (lane & 31) ^ (row & 15);
      const u16* gp = Sv + (size_t)row*DSEQ + sub*256 + (g << 3);
      __builtin_amdgcn_global_load_lds(
          (const AS1 void*)gp, (AS3 void*)(Slds + bs + j*512), 16, 0, 0);
    }
  };
  auto stage_reg = [&](int sub) {              // fp32 fallback
    const int bs = (sub & 1) * 32768;          // bytes
    #pragma unroll 2
    for (int it = 0; it < 8; ++it) {
      int f = it*256 + tid, row = f >> 5, q = f & 31;
      int g = q ^ (row & 15);
      const float4* sp = (const float4*)(Sf + (size_t)row*DSEQ + sub*256 + g*8);
      float4 v0 = sp[0], v1 = sp[1];
      bf16x8 wv;
      wv[0]=(short)f2bf(v0.x); wv[1]=(short)f2bf(v0.y);
      wv[2]=(short)f2bf(v0.z); wv[3]=(short)f2bf(v0.w);
      wv[4]=(short)f2bf(v1.x); wv[5]=(short)f2bf(v1.y);
      wv[6]=(short)f2bf(v1.z); wv[7]=(short)f2bf(v1.w);
      *(bf16x8*)((char*)Slds + bs + row*512 + q*16) = wv;
    }
  };

  f32x4 acc[4][4];
  #pragma unroll
  for (int rt = 0; rt < 4; ++rt)
    #pragma unroll
    for (int c = 0; c < 4; ++c) acc[rt][c] = {0.f,0.f,0.f,0.f};

  // B prefetch, distance 4: bA..bD hold steps g, g+1, g+2, g+3
  bf16x8 bA[4], bB[4], bC[4], bD[4];
  if (BF16SRC) stage_gl(0);
  #pragma unroll
  for (int c = 0; c < 4; ++c) bA[c] = *(const bf16x8*)(wb + (size_t)0*WC_KSTRIDE + c*512);
  #pragma unroll
  for (int c = 0; c < 4; ++c) bB[c] = *(const bf16x8*)(wb + (size_t)1*WC_KSTRIDE + c*512);
  #pragma unroll
  for (int c = 0; c < 4; ++c) bC[c] = *(const bf16x8*)(wb + (size_t)2*WC_KSTRIDE + c*512);
  #pragma unroll
  for (int c = 0; c < 4; ++c) bD[c] = *(const bf16x8*)(wb + (size_t)3*WC_KSTRIDE + c*512);
  if (BF16SRC) __syncthreads();

  // one k-step: consume BUF (holds step s*8+kk), refill it with step +4
#define KSTEP(BUF, kk)                                                        \
  do {                                                                        \
    const int colb = ((kk)*64 + lhi*16) ^ swz;                                \
    __builtin_amdgcn_s_setprio(1);                                            \
    _Pragma("unroll")                                                         \
    for (int rt = 0; rt < 4; ++rt) {                                          \
      bf16x8 af = *(const bf16x8*)(cb + arow[rt] + colb);                     \
      acc[rt][0] = __builtin_amdgcn_mfma_f32_16x16x32_bf16(af, BUF[0], acc[rt][0], 0,0,0); \
      acc[rt][1] = __builtin_amdgcn_mfma_f32_16x16x32_bf16(af, BUF[1], acc[rt][1], 0,0,0); \
      acc[rt][2] = __builtin_amdgcn_mfma_f32_16x16x32_bf16(af, BUF[2], acc[rt][2], 0,0,0); \
      acc[rt][3] = __builtin_amdgcn_mfma_f32_16x16x32_bf16(af, BUF[3], acc[rt][3], 0,0,0); \
    }                                                                         \
    __builtin_amdgcn_s_setprio(0);                                            \
    if (MODE != 1) {                                                          \
      const int kn = (s*8 + (kk) + 4) & 31;                                   \
      _Pragma("unroll")                                                       \
      for (int c = 0; c < 4; ++c)                                             \
        BUF[c] = *(const bf16x8*)(wb + (size_t)kn*WC_KSTRIDE + c*512);        \
    }                                                                         \
  } while (0)

  #pragma unroll
  for (int s = 0; s < 4; ++s) {
    if (BF16SRC) {
      if (MODE != 2 && s < 3) stage_gl(s + 1);   // issue-early
    } else {
      stage_reg(s);
      __syncthreads();
    }
    const char* cb = (const char*)Slds + (s & 1)*32768;
    KSTEP(bA, 0); KSTEP(bB, 1); KSTEP(bC, 2); KSTEP(bD, 3);
    KSTEP(bA, 4); KSTEP(bB, 5); KSTEP(bC, 6); KSTEP(bD, 7);
    __syncthreads();
  }
#undef KSTEP

  if (!isV) {
    // K-proj: tanh, dot with Q over 64 k-cols, reduce -> logit per row
    const float* Qb = Q + ((size_t)b*H_ + h)*DK_;
    float q[4];
    #pragma unroll
    for (int c = 0; c < 4; ++c) q[c] = Qb[16*c + llo];
    #pragma unroll
    for (int rt = 0; rt < 4; ++rt) {
      #pragma unroll
      for (int r = 0; r < 4; ++r) {
        float pl = q[0]*tanhf(acc[rt][0][r]) + q[1]*tanhf(acc[rt][1][r])
                 + q[2]*tanhf(acc[rt][2][r]) + q[3]*tanhf(acc[rt][3][r]);
        pl += __shfl_xor(pl, 1); pl += __shfl_xor(pl, 2);
        pl += __shfl_xor(pl, 4); pl += __shfl_xor(pl, 8);
        if (llo == 0) lpart[hp][rt*16 + lhi*4 + r] = pl;
      }
    }
  } else {
    // V-proj: exact gelu in place
    #pragma unroll
    for (int rt = 0; rt < 4; ++rt)
      #pragma unroll
      for (int c = 0; c < 4; ++c)
        #pragma unroll
        for (int r = 0; r < 4; ++r) {
          float x = acc[rt][c][r];
          acc[rt][c][r] = 0.5f*x*(1.f + erff(x*0.70710678118654752f));
        }
  }
  __syncthreads();

  if (isV) {
    // softmax stats over this tile's 64 rows (lane <-> row)
    float lg = lpart[hp][lane] * 0.125f;   // 1/sqrt(64)
    float mx = lg;
    #pragma unroll
    for (int mk = 1; mk < 64; mk <<= 1) mx = fmaxf(mx, __shfl_xor(mx, mk));
    float ev = __expf(lg - mx);
    float sv = ev;
    #pragma unroll
    for (int mk = 1; mk < 64; mk <<= 1) sv += __shfl_xor(sv, mk);

    float er[16];
    #pragma unroll
    for (int rt = 0; rt < 4; ++rt)
      #pragma unroll
      for (int r = 0; r < 4; ++r)
        er[rt*4 + r] = __shfl(ev, rt*16 + lhi*4 + r);

    float* pt = part + (((size_t)b*H_ + h)*NT + t)*PSTRIDE;
    #pragma unroll
    for (int c = 0; c < 4; ++c) {
      float y = 0.f;
      #pragma unroll
      for (int rt = 0; rt < 4; ++rt)
        #pragma unroll
        for (int r = 0; r < 4; ++r)
          y += er[rt*4 + r]*acc[rt][c][r];
      y += __shfl_xor(y, 16); y += __shfl_xor(y, 32);
      if (lhi == 0) pt[2 + 16*c + llo] = y;
    }
    if (lane == 0) { pt[0] = mx; pt[1] = sv; }
  }
}

// merge NT tile-partials per (b,h); grid (H, B), block 64 (v = thread)
__global__ void finalize_kernel(const float* __restrict__ part,
                                float* __restrict__ out) {
  const int h = blockIdx.x, b = blockIdx.y, v = threadIdx.x;
  const float* p = part + ((size_t)b*H_ + h)*(size_t)NT*PSTRIDE;
  float M = -3.0e38f;
  for (int tt = 0; tt < NT; ++tt) M = fmaxf(M, p[tt*PSTRIDE]);
  float ss = 0.f, y = 0.f;
  for (int tt = 0; tt < NT; ++tt) {
    float w = expf(p[tt*PSTRIDE] - M);
    ss += w*p[tt*PSTRIDE + 1];
    y  += w*p[tt*PSTRIDE + 2 + v];
  }
  out[((size_t)b*H_ + h)*DV_ + v] = y/ss;
}

extern "C" void kernel_launch(void* const* d_in, const int* in_sizes, int n_in,
                              void* d_out, int out_size, void* d_ws, size_t ws_size,
                              hipStream_t stream) {
  const float* X  = (const float*)d_in[0];
  const float* S  = (const float*)d_in[1];
  const float* Wq = (const float*)d_in[2];
  const float* Wk = (const float*)d_in[3];
  const float* Wv = (const float*)d_in[4];
  float* out = (float*)d_out;

  char* ws = (char*)d_ws;
  u16*   Wc    = (u16*)ws;                              // 4 MiB
  float* Qbuf  = (float*)(ws + (4u<<20));               // 128 KiB
  float* part  = (float*)(ws + (4u<<20) + (128u<<10));  // ~4.3 MiB (ends ~8.5)
  float* partd = (float*)(ws + (10u<<20));              // diag scratch ~4.3 MiB
  u16*   Sb    = (u16*)(ws + (16u<<20));                // 128 MiB (optional)
  const bool useBf = ws_size >= (144ull << 20);

  pack_w_kernel  <<<dim3(H_, 128),  256, 0, stream>>>(Wk, Wv, Wc);
  q_proj_kernel  <<<dim3(H_, B_/4),  64, 0, stream>>>(X, Wq, Qbuf);
  if (useBf) {
    s2bf_kernel         <<<dim3(4096), 256, 0, stream>>>(S, Sb);
    fused_kernel<1,0>   <<<dim3(NT*B_*8), 256, 0, stream>>>(S, Sb, Wc, Qbuf, part);
  } else {
    fused_kernel<0,0>   <<<dim3(NT*B_*8), 256, 0, stream>>>(S, Sb, Wc, Qbuf, part);
  }
  finalize_kernel<<<dim3(H_, B_),    64, 0, stream>>>(part, out);
  if (useBf) {
    // 1/8-grid diagnostics (write to scratch; rocprof rows decompose cost)
    fused_kernel<1,1>   <<<dim3(1024), 256, 0, stream>>>(S, Sb, Wc, Qbuf, partd);
    fused_kernel<1,2>   <<<dim3(1024), 256, 0, stream>>>(S, Sb, Wc, Qbuf, partd);
  }
}

// Round 11
// 460.547 us; speedup vs baseline: 1.3307x; 1.3307x over previous
//
#include <hip/hip_runtime.h>
#include <math.h>

#define B_   32
#define L_   2048
#define DSEQ 1024
#define DGLB 1024
#define H_   16
#define DK_  64
#define DV_  64
#define LT   64
#define NT   (L_/LT)      // 32
#define PSTRIDE 66        // m, s, y[64]

// Wc2 layout: [h][ks(32)][j(128)][e(32)] bf16; d = ks*32 + e
#define WC_KSTRIDE 4096            // 128*32 elems per k-step
#define WC_HSTRIDE 131072          // 32*4096 elems per head

#define AS1 __attribute__((address_space(1)))
#define AS3 __attribute__((address_space(3)))

using u16    = unsigned short;
using bf16x8 = __attribute__((ext_vector_type(8))) short;
using f32x4  = __attribute__((ext_vector_type(4))) float;

__device__ __forceinline__ u16 f2bf(float x) {
  union { float f; unsigned int u; } v; v.f = x;
  return (u16)((v.u + 0x7fffu + ((v.u >> 16) & 1u)) >> 16);   // RNE
}

// tanh via exp2 identity: 1 - 2/(1+2^(x*2*log2e)). ~6 instr, err ~1ulp-ish.
__device__ __forceinline__ float tanh_fast(float x) {
  float e = __builtin_exp2f(x * 2.885390081777927f);   // 2*log2(e)
  return 1.f - 2.f/(e + 1.f);
}

// erf, Abramowitz-Stegun 7.1.26, |err| < 1.5e-7. ~12 instr.
__device__ __forceinline__ float erf_fast(float x) {
  float ax = fabsf(x);
  float t  = 1.f/(1.f + 0.3275911f*ax);
  float p  = t*(0.254829592f + t*(-0.284496736f + t*(1.421413741f +
             t*(-1.453152027f + t*1.061405429f))));
  float e  = __builtin_exp2f(-ax*ax*1.4426950408889634f);  // e^{-x^2}
  float r  = 1.f - p*e;
  return copysignf(r, x);
}

// Wc2[h][d>>5][j][d&31]: j<64 -> Wk[h,:,j], else Wv[h,:,j-64]
__global__ void pack_w_kernel(const float* __restrict__ Wk,
                              const float* __restrict__ Wv,
                              u16* __restrict__ Wc) {
  const int h = blockIdx.x, j = blockIdx.y;
  const float* src = (j < DK_) ? (Wk + (size_t)h*DSEQ*DK_ + j)
                               : (Wv + (size_t)h*DSEQ*DV_ + (j - DK_));
  u16* dst = Wc + (size_t)h*WC_HSTRIDE + (size_t)j*32;
  for (int d = threadIdx.x; d < DSEQ; d += blockDim.x)
    dst[(size_t)(d >> 5)*WC_KSTRIDE + (d & 31)] = f2bf(src[(size_t)d*64]);
}

// S (fp32) -> Sb (bf16), flat; 8-elem granules, coalesced
__global__ void s2bf_kernel(const float* __restrict__ S, u16* __restrict__ Sb) {
  const size_t G = (size_t)B_*L_*DSEQ/8;
  for (size_t i = (size_t)blockIdx.x*256 + threadIdx.x; i < G; i += (size_t)4096*256) {
    const float4* sp = (const float4*)(S + i*8);
    float4 v0 = sp[0], v1 = sp[1];
    bf16x8 wv;
    wv[0]=(short)f2bf(v0.x); wv[1]=(short)f2bf(v0.y);
    wv[2]=(short)f2bf(v0.z); wv[3]=(short)f2bf(v0.w);
    wv[4]=(short)f2bf(v1.x); wv[5]=(short)f2bf(v1.y);
    wv[6]=(short)f2bf(v1.z); wv[7]=(short)f2bf(v1.w);
    *(bf16x8*)(Sb + i*8) = wv;
  }
}

// Q[b][h][k] = tanh(sum_d X[b,d]*Wq[h,d,k]); grid (H, B/4), block 64
__global__ void q_proj_kernel(const float* __restrict__ X,
                              const float* __restrict__ Wq,
                              float* __restrict__ Q) {
  const int h = blockIdx.x, b0 = blockIdx.y*4, k = threadIdx.x;
  const float* w = Wq + (size_t)h*DGLB*DK_ + k;
  float a0=0.f, a1=0.f, a2=0.f, a3=0.f;
  for (int d = 0; d < DGLB; ++d) {
    float wv = w[(size_t)d*DK_];
    a0 += X[(size_t)(b0+0)*DGLB + d]*wv;
    a1 += X[(size_t)(b0+1)*DGLB + d]*wv;
    a2 += X[(size_t)(b0+2)*DGLB + d]*wv;
    a3 += X[(size_t)(b0+3)*DGLB + d]*wv;
  }
  Q[((size_t)(b0+0)*H_+h)*DK_+k] = tanhf(a0);
  Q[((size_t)(b0+1)*H_+h)*DK_+k] = tanhf(a1);
  Q[((size_t)(b0+2)*H_+h)*DK_+k] = tanhf(a2);
  Q[((size_t)(b0+3)*H_+h)*DK_+k] = tanhf(a3);
}

// grid: 8192 linear blocks, 256 threads = 4 waves, 3 blocks/CU.
// slot=id&7 -> XCD = head-pair (Wc2 slice 512 KB L2-hot); tile offset-
// diagonal across XCDs. Wave w = (head hp=w>>1, K|V=w&1); 64x64 tile,
// acc[4][4]. K pipelined in 8 sub-tiles of 128 via 2x16KB LDS dbuf
// (33 KB/block -> 3 blocks/CU; launch_bounds(256,3) -> ~170-reg budget,
// current live set 164 fits). Stage issue-early; B prefetch distance 4.
// Rows are 256 B (16 granules of 16 B); swizzle: granule g at row r sits
// at physical slot g^(r&15) (applied to global src for gload_lds).
template<int BF16SRC>
__global__ __launch_bounds__(256, 3) void fused_kernel(
    const float* __restrict__ S, const u16* __restrict__ Sb,
    const u16* __restrict__ Wc, const float* __restrict__ Q,
    float* __restrict__ part) {
  __shared__ u16   Slds[2*64*128];   // 2 x 16 KB, rows 256 B
  __shared__ float lpart[2][64];

  const int id   = blockIdx.x;
  const int slot = id & 7;           // XCD = head-pair
  const int m    = id >> 3;
  const int tile = (m + (slot << 7)) & 1023;
  const int t    = tile & (NT-1), b = tile >> 5;

  const int tid  = threadIdx.x;
  const int wave = tid >> 6, lane = tid & 63;
  const int lhi  = lane >> 4, llo = lane & 15;
  const int isV  = wave & 1,  hp  = wave >> 1;
  const int h    = slot*2 + hp;

  const u16* wb = Wc + (size_t)h*WC_HSTRIDE + (size_t)(isV*64 + llo)*32 + lhi*8;
  int arow[4];
  #pragma unroll
  for (int rt = 0; rt < 4; ++rt) arow[rt] = (rt*16 + llo)*256;  // bytes

  const u16*   Sv = Sb + ((size_t)b*L_ + (size_t)t*LT)*DSEQ;
  const float* Sf = S  + ((size_t)b*L_ + (size_t)t*LT)*DSEQ;

  // stage sub-tile (64 rows x 128 k = 16 KB) into buf[sub&1]:
  // chunk j (1 KB) = rows 4j..4j+3; lane l -> row 4j+(l>>4), slot q=l&15,
  // logical granule g = q ^ (row&15) fetched from global (src swizzle).
  auto stage_gl = [&](int sub) {
    const int bs = (sub & 1) * 8192;           // u16 offset (16 KB)
    #pragma unroll
    for (int it = 0; it < 4; ++it) {
      const int j   = wave*4 + it;
      const int row = 4*j + (lane >> 4);
      const int g   = (lane & 15) ^ (row & 15);
      const u16* gp = Sv + (size_t)row*DSEQ + sub*128 + (g << 3);
      __builtin_amdgcn_global_load_lds(
          (const AS1 void*)gp, (AS3 void*)(Slds + bs + j*512), 16, 0, 0);
    }
  };
  auto stage_reg = [&](int sub) {              // fp32 fallback
    const int bs = (sub & 1) * 16384;          // bytes
    #pragma unroll
    for (int it = 0; it < 4; ++it) {
      int f = it*256 + tid, row = f >> 4, q = f & 15;
      int g = q ^ (row & 15);
      const float4* sp = (const float4*)(Sf + (size_t)row*DSEQ + sub*128 + g*8);
      float4 v0 = sp[0], v1 = sp[1];
      bf16x8 wv;
      wv[0]=(short)f2bf(v0.x); wv[1]=(short)f2bf(v0.y);
      wv[2]=(short)f2bf(v0.z); wv[3]=(short)f2bf(v0.w);
      wv[4]=(short)f2bf(v1.x); wv[5]=(short)f2bf(v1.y);
      wv[6]=(short)f2bf(v1.z); wv[7]=(short)f2bf(v1.w);
      *(bf16x8*)((char*)Slds + bs + row*256 + q*16) = wv;
    }
  };

  f32x4 acc[4][4];
  #pragma unroll
  for (int rt = 0; rt < 4; ++rt)
    #pragma unroll
    for (int c = 0; c < 4; ++c) acc[rt][c] = {0.f,0.f,0.f,0.f};

  // B prefetch, distance 4: bA..bD hold steps g..g+3
  bf16x8 bA[4], bB[4], bC[4], bD[4];
  if (BF16SRC) stage_gl(0);
  #pragma unroll
  for (int c = 0; c < 4; ++c) bA[c] = *(const bf16x8*)(wb + (size_t)0*WC_KSTRIDE + c*512);
  #pragma unroll
  for (int c = 0; c < 4; ++c) bB[c] = *(const bf16x8*)(wb + (size_t)1*WC_KSTRIDE + c*512);
  #pragma unroll
  for (int c = 0; c < 4; ++c) bC[c] = *(const bf16x8*)(wb + (size_t)2*WC_KSTRIDE + c*512);
  #pragma unroll
  for (int c = 0; c < 4; ++c) bD[c] = *(const bf16x8*)(wb + (size_t)3*WC_KSTRIDE + c*512);
  if (BF16SRC) __syncthreads();

  // one k-step (32 elems): consume BUF (step s*4+kk), refill with step +4
#define KSTEP(BUF, kk)                                                        \
  do {                                                                        \
    const int colb = (((kk)*4 + lhi) ^ llo) << 4;                             \
    __builtin_amdgcn_s_setprio(1);                                            \
    _Pragma("unroll")                                                         \
    for (int rt = 0; rt < 4; ++rt) {                                          \
      bf16x8 af = *(const bf16x8*)(cb + arow[rt] + colb);                     \
      acc[rt][0] = __builtin_amdgcn_mfma_f32_16x16x32_bf16(af, BUF[0], acc[rt][0], 0,0,0); \
      acc[rt][1] = __builtin_amdgcn_mfma_f32_16x16x32_bf16(af, BUF[1], acc[rt][1], 0,0,0); \
      acc[rt][2] = __builtin_amdgcn_mfma_f32_16x16x32_bf16(af, BUF[2], acc[rt][2], 0,0,0); \
      acc[rt][3] = __builtin_amdgcn_mfma_f32_16x16x32_bf16(af, BUF[3], acc[rt][3], 0,0,0); \
    }                                                                         \
    __builtin_amdgcn_s_setprio(0);                                            \
    {                                                                         \
      const int kn = (s*4 + (kk) + 4) & 31;                                   \
      _Pragma("unroll")                                                       \
      for (int c = 0; c < 4; ++c)                                             \
        BUF[c] = *(const bf16x8*)(wb + (size_t)kn*WC_KSTRIDE + c*512);        \
    }                                                                         \
  } while (0)

  #pragma unroll
  for (int s = 0; s < 8; ++s) {
    if (BF16SRC) {
      if (s < 7) stage_gl(s + 1);              // issue-early
    } else {
      stage_reg(s);
      __syncthreads();
    }
    const char* cb = (const char*)Slds + (s & 1)*16384;
    KSTEP(bA, 0); KSTEP(bB, 1); KSTEP(bC, 2); KSTEP(bD, 3);
    __syncthreads();
  }
#undef KSTEP

  if (!isV) {
    // K-proj: tanh, dot with Q over 64 k-cols, reduce -> logit per row
    const float* Qb = Q + ((size_t)b*H_ + h)*DK_;
    float q[4];
    #pragma unroll
    for (int c = 0; c < 4; ++c) q[c] = Qb[16*c + llo];
    #pragma unroll
    for (int rt = 0; rt < 4; ++rt) {
      #pragma unroll
      for (int r = 0; r < 4; ++r) {
        float pl = q[0]*tanh_fast(acc[rt][0][r]) + q[1]*tanh_fast(acc[rt][1][r])
                 + q[2]*tanh_fast(acc[rt][2][r]) + q[3]*tanh_fast(acc[rt][3][r]);
        pl += __shfl_xor(pl, 1); pl += __shfl_xor(pl, 2);
        pl += __shfl_xor(pl, 4); pl += __shfl_xor(pl, 8);
        if (llo == 0) lpart[hp][rt*16 + lhi*4 + r] = pl;
      }
    }
  } else {
    // V-proj: gelu (erf via A&S 7.1.26, |err|<1.5e-7) in place
    #pragma unroll
    for (int rt = 0; rt < 4; ++rt)
      #pragma unroll
      for (int c = 0; c < 4; ++c)
        #pragma unroll
        for (int r = 0; r < 4; ++r) {
          float x = acc[rt][c][r];
          acc[rt][c][r] = 0.5f*x*(1.f + erf_fast(x*0.70710678118654752f));
        }
  }
  __syncthreads();

  if (isV) {
    // softmax stats over this tile's 64 rows (lane <-> row)
    float lg = lpart[hp][lane] * 0.125f;   // 1/sqrt(64)
    float mx = lg;
    #pragma unroll
    for (int mk = 1; mk < 64; mk <<= 1) mx = fmaxf(mx, __shfl_xor(mx, mk));
    float ev = __expf(lg - mx);
    float sv = ev;
    #pragma unroll
    for (int mk = 1; mk < 64; mk <<= 1) sv += __shfl_xor(sv, mk);

    float er[16];
    #pragma unroll
    for (int rt = 0; rt < 4; ++rt)
      #pragma unroll
      for (int r = 0; r < 4; ++r)
        er[rt*4 + r] = __shfl(ev, rt*16 + lhi*4 + r);

    float* pt = part + (((size_t)b*H_ + h)*NT + t)*PSTRIDE;
    #pragma unroll
    for (int c = 0; c < 4; ++c) {
      float y = 0.f;
      #pragma unroll
      for (int rt = 0; rt < 4; ++rt)
        #pragma unroll
        for (int r = 0; r < 4; ++r)
          y += er[rt*4 + r]*acc[rt][c][r];
      y += __shfl_xor(y, 16); y += __shfl_xor(y, 32);
      if (lhi == 0) pt[2 + 16*c + llo] = y;
    }
    if (lane == 0) { pt[0] = mx; pt[1] = sv; }
  }
}

// merge NT tile-partials per (b,h); grid (H, B), block 64 (v = thread)
__global__ void finalize_kernel(const float* __restrict__ part,
                                float* __restrict__ out) {
  const int h = blockIdx.x, b = blockIdx.y, v = threadIdx.x;
  const float* p = part + ((size_t)b*H_ + h)*(size_t)NT*PSTRIDE;
  float M = -3.0e38f;
  for (int tt = 0; tt < NT; ++tt) M = fmaxf(M, p[tt*PSTRIDE]);
  float ss = 0.f, y = 0.f;
  for (int tt = 0; tt < NT; ++tt) {
    float w = expf(p[tt*PSTRIDE] - M);
    ss += w*p[tt*PSTRIDE + 1];
    y  += w*p[tt*PSTRIDE + 2 + v];
  }
  out[((size_t)b*H_ + h)*DV_ + v] = y/ss;
}

extern "C" void kernel_launch(void* const* d_in, const int* in_sizes, int n_in,
                              void* d_out, int out_size, void* d_ws, size_t ws_size,
                              hipStream_t stream) {
  const float* X  = (const float*)d_in[0];
  const float* S  = (const float*)d_in[1];
  const float* Wq = (const float*)d_in[2];
  const float* Wk = (const float*)d_in[3];
  const float* Wv = (const float*)d_in[4];
  float* out = (float*)d_out;

  char* ws = (char*)d_ws;
  u16*   Wc    = (u16*)ws;                              // 4 MiB
  float* Qbuf  = (float*)(ws + (4u<<20));               // 128 KiB
  float* part  = (float*)(ws + (4u<<20) + (128u<<10));  // ~4.3 MiB
  u16*   Sb    = (u16*)(ws + (16u<<20));                // 128 MiB (optional)
  const bool useBf = ws_size >= (144ull << 20);

  pack_w_kernel  <<<dim3(H_, 128),  256, 0, stream>>>(Wk, Wv, Wc);
  q_proj_kernel  <<<dim3(H_, B_/4),  64, 0, stream>>>(X, Wq, Qbuf);
  if (useBf) {
    s2bf_kernel         <<<dim3(4096), 256, 0, stream>>>(S, Sb);
    fused_kernel<1>     <<<dim3(NT*B_*8), 256, 0, stream>>>(S, Sb, Wc, Qbuf, part);
  } else {
    fused_kernel<0>     <<<dim3(NT*B_*8), 256, 0, stream>>>(S, Sb, Wc, Qbuf, part);
  }
  finalize_kernel<<<dim3(H_, B_),    64, 0, stream>>>(part, out);
}